// Round 10
// baseline (137.076 us; speedup 1.0000x reference)
//
#include <hip/hip_runtime.h>
#include <hip/hip_bf16.h>

#define NB 1024
#define LQ 20
#define LD 200
#define E4 32      // 128 floats / 4
#define NK 21
#define NTILE 13   // ceil(208/16) j-tiles of 16 d-cols
#define MDUMMY 3.0f   // ladder input whose every contribution underflows to exact 0

typedef __attribute__((ext_vector_type(8))) short bf16x8;   // 8 bf16 = 4 VGPRs
typedef __attribute__((ext_vector_type(4))) float f32x4;
typedef __attribute__((ext_vector_type(2))) float f32x2;    // v_pk_*_f32 target

// Packed f32->bf16 RNE via the cast path (compiler emits v_cvt_pk_bf16_f32).
__device__ __forceinline__ unsigned cvt2(float lo, float hi) {
    __hip_bfloat162 h = __float22bfloat162_rn(make_float2(lo, hi));
    unsigned u;
    __builtin_memcpy(&u, &h, 4);
    return u;
}

__device__ __forceinline__ bf16x8 pack8(float4 f0, float4 f1) {
    union { unsigned u[4]; bf16x8 v; } r;
    r.u[0] = cvt2(f0.x, f0.y);
    r.u[1] = cvt2(f0.z, f0.w);
    r.u[2] = cvt2(f1.x, f1.y);
    r.u[3] = cvt2(f1.z, f1.w);
    return r.v;
}

__device__ __forceinline__ f32x2 fma2(f32x2 a, f32x2 b, f32x2 c) {
    return __builtin_elementwise_fma(a, b, c);
}

// Packed norm accumulation from RAW f32 (v_pk_fma_f32: 4 insts per 8 floats).
__device__ __forceinline__ f32x2 sqacc(float4 f0, float4 f1, f32x2 s) {
    f32x2 a = {f0.x, f0.y}, b = {f0.z, f0.w};
    f32x2 c = {f1.x, f1.y}, d = {f1.z, f1.w};
    s = fma2(a, a, s); s = fma2(b, b, s);
    s = fma2(c, c, s); s = fma2(d, d, s);
    return s;
}

__device__ __forceinline__ float fast_exp2(float x) {
#if __has_builtin(__builtin_amdgcn_exp2f)
    return __builtin_amdgcn_exp2f(x);
#else
    return __expf(x * 0.69314718056f);
#endif
}

// phi_{10+-n}(m) = p * w^n * D_n, x = m-0.05, p = e^{-50x^2}, w = e^{+-10x},
// D_n = e^{-n^2/2} constant. k=20 (exact kernel) handled by the CALLER:
// underflows to exact 0.0f unless m > 0.98.
#define DN0 0.60653066f
#define DN1 0.13533528f
#define DN2 1.1108997e-2f
#define DN3 3.3546263e-4f
#define DN4 3.7266532e-6f
#define DN5 1.5229979e-8f
#define DN6 2.2897348e-11f
#define DN7 1.2664166e-14f
#define DN8 2.5767912e-18f
#define DN9 1.9287498e-22f

__device__ __forceinline__ f32x2 pk_exp2(f32x2 a) {
    f32x2 r; r.x = fast_exp2(a.x); r.y = fast_exp2(a.y); return r;
}

// Packed Gaussian ladder for k=0..19 (two m-values per pass).
__device__ __forceinline__ void rbf2(f32x2 m, f32x2* S) {
    const float DN[10] = {DN0, DN1, DN2, DN3, DN4, DN5, DN6, DN7, DN8, DN9};
    const f32x2 x = m - 0.05f;
    const f32x2 p = pk_exp2(x * x * -72.13475204f);
    S[10] += p;
    f32x2 w = pk_exp2(x * 14.4269504089f);           // e^{10x}
    f32x2 q = p;
    #pragma unroll
    for (int n = 1; n <= 9; ++n) {
        q = q * w;
        S[10 + n] = fma2(q, (f32x2)(DN[n - 1]), S[10 + n]);
    }
    w = pk_exp2(x * -14.4269504089f);                // e^{-10x}
    q = p;
    #pragma unroll
    for (int n = 1; n <= 10; ++n) {
        q = q * w;
        S[10 - n] = fma2(q, (f32x2)(DN[n - 1]), S[10 - n]);
    }
}

// Issue the 8 scattered 16B loads for one D-tile into a named register buffer.
#define LOAD8(P, id) { \
    const float4* db_ = emb4 + (size_t)(unsigned)(id) * E4; \
    P##0 = db_[quad * 2];      P##1 = db_[quad * 2 + 1]; \
    P##2 = db_[8 + quad * 2];  P##3 = db_[8 + quad * 2 + 1]; \
    P##4 = db_[16 + quad * 2]; P##5 = db_[16 + quad * 2 + 1]; \
    P##6 = db_[24 + quad * 2]; P##7 = db_[24 + quad * 2 + 1]; }

// One pipeline step: consume buffer P for tile (wv+2*TI), then re-issue P for
// tile+4 (2-deep pipeline: the other buffer's loads stay in flight).
#define STEP(TI, P) { \
    const int tile = wv + 2 * (TI); \
    if (tile < NTILE) { \
        if (tile == NTILE - 1 && c >= (LD - (NTILE - 1) * 16)) { \
            P##0 = P##1 = P##2 = P##3 = P##4 = P##5 = P##6 = P##7 = \
                make_float4(0.f, 0.f, 0.f, 0.f); \
        } \
        f32x2 dq = {0.f, 0.f}; \
        f32x4 acc0 = {0.f, 0.f, 0.f, 0.f}; \
        f32x4 acc1 = {0.f, 0.f, 0.f, 0.f}; \
        { \
            dq = sqacc(P##0, P##1, dq); \
            bf16x8 bFk = pack8(P##0, P##1); \
            acc0 = __builtin_amdgcn_mfma_f32_16x16x32_bf16(bFk, aF[0][0], acc0, 0, 0, 0); \
            acc1 = __builtin_amdgcn_mfma_f32_16x16x32_bf16(bFk, aF[1][0], acc1, 0, 0, 0); \
        } \
        { \
            dq = sqacc(P##2, P##3, dq); \
            bf16x8 bFk = pack8(P##2, P##3); \
            acc0 = __builtin_amdgcn_mfma_f32_16x16x32_bf16(bFk, aF[0][1], acc0, 0, 0, 0); \
            acc1 = __builtin_amdgcn_mfma_f32_16x16x32_bf16(bFk, aF[1][1], acc1, 0, 0, 0); \
        } \
        { \
            dq = sqacc(P##4, P##5, dq); \
            bf16x8 bFk = pack8(P##4, P##5); \
            acc0 = __builtin_amdgcn_mfma_f32_16x16x32_bf16(bFk, aF[0][2], acc0, 0, 0, 0); \
            acc1 = __builtin_amdgcn_mfma_f32_16x16x32_bf16(bFk, aF[1][2], acc1, 0, 0, 0); \
        } \
        { \
            dq = sqacc(P##6, P##7, dq); \
            bf16x8 bFk = pack8(P##6, P##7); \
            acc0 = __builtin_amdgcn_mfma_f32_16x16x32_bf16(bFk, aF[0][3], acc0, 0, 0, 0); \
            acc1 = __builtin_amdgcn_mfma_f32_16x16x32_bf16(bFk, aF[1][3], acc1, 0, 0, 0); \
        } \
        if (tile + 4 < NTILE) {                  /* re-issue P for tile+4 */ \
            LOAD8(P, idn); \
            const int jn_ = (tile + 6) * 16 + c; \
            idn = di[b * LD + (jn_ < LD ? jn_ : LD - 1)]; \
        } \
        float dsq = dq.x + dq.y; \
        dsq += __shfl_xor(dsq, 16); \
        dsq += __shfl_xor(dsq, 32); \
        const float rdc = rsqrtf(dsq + 1e-6f); \
        float rdv0 = __shfl(rdc, quad * 4); \
        float rdv1 = __shfl(rdc, quad * 4 + 1); \
        float rdv2 = __shfl(rdc, quad * 4 + 2); \
        float rdv3 = __shfl(rdc, quad * 4 + 3); \
        const f32x2 r01 = {rdv0, rdv1}, r23 = {rdv2, rdv3}; \
        f32x2 ma = {acc0[0], acc0[1]}; \
        f32x2 mb = {acc0[2], acc0[3]}; \
        ma = ma * r01 * rqA; \
        mb = mb * r23 * rqA; \
        rbf2(ma, Sp); \
        rbf2(mb, Sp); \
        const float mx = fmaxf(fmaxf(ma.x, ma.y), fmaxf(mb.x, mb.y)); \
        if (__any(mx > 0.98f)) { \
            const f32x2 da = ma - 1.0f, db2 = mb - 1.0f; \
            Sp[20] += pk_exp2(da * da * -721347.5204f); \
            Sp[20] += pk_exp2(db2 * db2 * -721347.5204f); \
        } \
        f32x2 n01 = {acc1[0], acc1[1]}; \
        f32x2 n23 = {acc1[2], acc1[3]}; \
        n01 = n01 * r01 * rqB; \
        n23 = n23 * r23 * rqB; \
        const int src = (lane & 48) | ((lane >> 2) & 3); \
        const float g0 = __shfl(n01.x, src); \
        const float g1 = __shfl(n01.y, src); \
        const float g2 = __shfl(n23.x, src); \
        const float g3 = __shfl(n23.y, src); \
        const int rsel = lane & 3; \
        mv[TI] = (rsel == 0) ? g0 : (rsel == 1) ? g1 : (rsel == 2) ? g2 : g3; \
    } else { \
        mv[TI] = MDUMMY; \
    } }

// One block per batch item, BOTH preds fused: waves {0,1}->pred0, {2,3}->pred1.
// Grid = 1024 = 4 blocks/CU fully resident. 2-deep register pipeline (A/B
// buffers): 16 loads in flight per wave; counted vmcnt keeps the other
// buffer's loads pending across each tile's compute.
__global__ __launch_bounds__(256, 2) void knrm_main(
    const int* __restrict__ q1, const int* __restrict__ d1,
    const int* __restrict__ q2, const int* __restrict__ d2,
    const float* __restrict__ emb,
    const float* __restrict__ W1, const float* __restrict__ b1,
    const float* __restrict__ W2, const float* __restrict__ b2,
    const float* __restrict__ W3, const float* __restrict__ b3,
    float* __restrict__ out)        // [NB]
{
    __shared__ float sPhiW[4][LQ][NK];   // per-wave partial sums, 6.72 KB
    __shared__ float sX[2][NK];
    __shared__ float sH1[2][10];
    __shared__ float sH2[2][5];

    const int b    = blockIdx.x;
    const int t    = threadIdx.x;
    const int lane = t & 63, wave = t >> 6;
    const int pred = wave >> 1, wv = wave & 1;   // wv: which half of the tiles
    const int c    = lane & 15, quad = lane >> 4;
    const int* __restrict__ qi = pred ? q2 : q1;
    const int* __restrict__ di = pred ? d2 : d1;
    const float4* emb4 = (const float4*)emb;

    // ---- ids ----
    const int qid0 = qi[b * LQ + c];
    const int r1   = 16 + c;
    const int qid1 = qi[b * LQ + (r1 < LQ ? r1 : LQ - 1)];
    const int j0   = wv * 16 + c;                          // j0 <= 31
    const int idA  = di[b * LD + j0];                      // tile wv
    const int idB  = di[b * LD + j0 + 32];                 // tile wv+2
    int idn        = di[b * LD + j0 + 64];                 // tile wv+4 (<=95<200)

    // ---- prologue: issue BOTH staged tiles ----
    float4 A0, A1, A2, A3, A4, A5, A6, A7;
    float4 B0, B1, B2, B3, B4, B5, B6, B7;
    LOAD8(A, idA);
    LOAD8(B, idB);

    // ---- Q fragments (B operand): cols i = c (Mt0) / 16+c (Mt1) ----
    bf16x8 aF[2][4];
    float rqA, rqB;
    {
        const float4* qb0 = emb4 + (size_t)(unsigned)qid0 * E4;
        const float4* qb1 = emb4 + (size_t)(unsigned)qid1 * E4;
        f32x2 q0 = {0.f, 0.f}, q1v = {0.f, 0.f};
        #pragma unroll
        for (int ks = 0; ks < 4; ++ks) {
            float4 f0 = qb0[ks * 8 + quad * 2];
            float4 f1 = qb0[ks * 8 + quad * 2 + 1];
            q0 = sqacc(f0, f1, q0);
            aF[0][ks] = pack8(f0, f1);
            float4 g0 = qb1[ks * 8 + quad * 2];
            float4 g1 = qb1[ks * 8 + quad * 2 + 1];
            q1v = sqacc(g0, g1, q1v);
            aF[1][ks] = pack8(g0, g1);
        }
        float qs0 = q0.x + q0.y, qs1 = q1v.x + q1v.y;
        if (c >= LQ - 16) {                      // pad q-rows 20..31 -> exact zeros
            #pragma unroll
            for (int ks = 0; ks < 4; ++ks) aF[1][ks] = (bf16x8)0;
            qs1 = 0.f;
        }
        qs0 += __shfl_xor(qs0, 16); qs0 += __shfl_xor(qs0, 32);
        qs1 += __shfl_xor(qs1, 16); qs1 += __shfl_xor(qs1, 32);
        rqA = rsqrtf(qs0 + 1e-6f);
        rqB = rsqrtf(qs1 + 1e-6f);
    }

    // ---- per-lane accumulators ----
    f32x2 Sp[NK];
    #pragma unroll
    for (int k = 0; k < NK; ++k) Sp[k] = (f32x2)(0.f);
    float mv[8];
    mv[7] = MDUMMY;

    // ---- 2-deep pipelined tile steps (A/B alternate; static indexing) ----
    STEP(0, A);
    STEP(1, B);
    STEP(2, A);
    STEP(3, B);
    STEP(4, A);
    STEP(5, B);
    STEP(6, A);

    // ---- deferred acc1 ladders: 4 packed passes over the buffered values ----
    f32x2 S1p[NK];
    #pragma unroll
    for (int k = 0; k < NK; ++k) S1p[k] = (f32x2)(0.f);
    #pragma unroll
    for (int pp = 0; pp < 4; ++pp) {
        f32x2 mm;
        mm.x = mv[2 * pp];
        mm.y = mv[2 * pp + 1];
        rbf2(mm, S1p);
        const f32x2 dd = mm - 1.0f;
        S1p[20] += pk_exp2(dd * dd * -721347.5204f);
    }

    // ---- reductions ----
    float S0f[NK], S1f[NK];
    #pragma unroll
    for (int k = 0; k < NK; ++k) {
        float s0 = Sp[k].x + Sp[k].y;
        s0 += __shfl_xor(s0, 16);
        s0 += __shfl_xor(s0, 32);
        S0f[k] = s0;
        float s1 = S1p[k].x + S1p[k].y;
        s1 += __shfl_xor(s1, 1);
        s1 += __shfl_xor(s1, 2);
        s1 += __shfl_xor(s1, 16);
        s1 += __shfl_xor(s1, 32);
        S1f[k] = s1;
    }
    if (quad == 0) {
        #pragma unroll
        for (int k = 0; k < NK; ++k) sPhiW[wave][c][k] = S0f[k];
    }
    if ((lane & 51) == 0) {                       // lanes 0,4,8,12 -> i = 16..19
        #pragma unroll
        for (int k = 0; k < NK; ++k) sPhiW[wave][16 + (lane >> 2)][k] = S1f[k];
    }
    __syncthreads();

    // ---- epilogue: waves 0/1 handle pred 0/1 in parallel ----
    const int ew = t >> 6, et = t & 63;

    // log1p + sum over i; subtract the 8 padded-j rows (each added phi_k(0))
    if (ew < 2 && et < NK) {
        const float mu_t = 0.1f * (float)et - 0.95f;
        const float pad  = (et < 20) ? 8.0f * fast_exp2(-72.13475204f * mu_t * mu_t) : 0.0f;
        float s = 0.f;
        #pragma unroll
        for (int i = 0; i < LQ; ++i) {
            const float v = sPhiW[2 * ew][i][et] + sPhiW[2 * ew + 1][i][et] - pad;
            s += __logf(1.0f + v);
        }
        sX[ew][et] = fmaxf(s, 0.f);   // relu (guards tiny negative from pad cancel)
    }
    __syncthreads();

    if (ew < 2 && et < 10) {
        float v = b1[et];
        #pragma unroll
        for (int k = 0; k < NK; ++k) v += W1[et * NK + k] * sX[ew][k];
        sH1[ew][et] = fmaxf(v, 0.f);
    }
    __syncthreads();

    if (ew < 2 && et < 5) {
        float v = b2[et];
        #pragma unroll
        for (int k = 0; k < 10; ++k) v += W2[et * 10 + k] * sH1[ew][k];
        sH2[ew][et] = fmaxf(v, 0.f);
    }
    __syncthreads();

    if (t == 0) {
        float l0 = b3[0], l1 = b3[0];
        #pragma unroll
        for (int k = 0; k < 5; ++k) {
            l0 += W3[k] * sH2[0][k];
            l1 += W3[k] * sH2[1][k];
        }
        out[b] = 1.0f / (1.0f + __expf(l1 - l0));   // sigmoid(l0 - l1)
    }
}

extern "C" void kernel_launch(void* const* d_in, const int* in_sizes, int n_in,
                              void* d_out, int out_size, void* d_ws, size_t ws_size,
                              hipStream_t stream) {
    knrm_main<<<NB, 256, 0, stream>>>(
        (const int*)d_in[0], (const int*)d_in[1],
        (const int*)d_in[2], (const int*)d_in[3],
        (const float*)d_in[4],
        (const float*)d_in[5], (const float*)d_in[6],
        (const float*)d_in[7], (const float*)d_in[8],
        (const float*)d_in[9], (const float*)d_in[10],
        (float*)d_out);
}